// Round 2
// baseline (131.513 us; speedup 1.0000x reference)
//
#include <hip/hip_runtime.h>
#include <hip/hip_bf16.h>

// RandomProjectionQuantizer:
//  x:(16,2048,320) f32, mask:(16,2048) i32 (exactly 16384 ones),
//  W:(16,320) f32, codebook:(8192,16) f32  ->  scalar int32 label
//  label = argmin over flattened (16384 x 8192) distance matrix, rows in
//  ascending masked-index order (jnp.nonzero order), first-index tie-break.
//
// R2: argmin = 4 rows/thread (no spill), 1024 blocks, codes via wave-uniform
// loads (s_load promotion) with A/B prefetch; project drops LDS-W (uniform
// s_load) -> HBM-bound; prep+c2 fused; finish fused into argmin via ticket.

#define NMASK   16384
#define D       320
#define CDIM    16
#define NCODES  8192

// ---------------- Kernel 1: chunk scan + codebook norms + init --------------
// bid 0: 512-chunk prefix scan of mask counts (chunk = 64 rows = 1 wave),
//        plus init of keys/counter. bid 1..16: c2[k] = ||codebook[k]||^2.
__global__ __launch_bounds__(512) void prep_kernel(const int* __restrict__ mask,
                                                   const float* __restrict__ cbk,
                                                   int* __restrict__ chunkpref,
                                                   float* __restrict__ c2,
                                                   unsigned long long* __restrict__ keys,
                                                   unsigned int* __restrict__ counter) {
  int tid = threadIdx.x;
  if (blockIdx.x == 0) {
    __shared__ int a[512], b[512];
    int wave = tid >> 6, lane = tid & 63;
    for (int j = 0; j < 64; ++j) {
      int c = wave * 64 + j;                     // 8 waves * 64 = 512 chunks
      int m = mask[c * 64 + lane];
      unsigned long long bal = __ballot(m != 0);
      if (lane == 0) a[c] = __popcll(bal);
    }
    __syncthreads();
    int* src = a; int* dst = b;
    for (int off = 1; off < 512; off <<= 1) {    // Hillis-Steele inclusive
      dst[tid] = src[tid] + (tid >= off ? src[tid - off] : 0);
      __syncthreads();
      int* t = src; src = dst; dst = t;
    }
    chunkpref[tid] = (tid == 0) ? 0 : src[tid - 1];
    if (tid < 8) keys[tid] = 0xFFFFFFFFFFFFFFFFull;
    if (tid == 8) *counter = 0u;
  } else {
    int k = (blockIdx.x - 1) * 512 + tid;        // 16 blocks * 512 = 8192
    const float4* p = (const float4*)(cbk + (long)k * CDIM);
    float s = 0.f;
#pragma unroll
    for (int q = 0; q < 4; ++q) {
      float4 v = p[q];
      s = fmaf(v.x, v.x, s); s = fmaf(v.y, v.y, s);
      s = fmaf(v.z, v.z, s); s = fmaf(v.w, v.w, s);
    }
    c2[k] = s;
  }
}

// ---------------- Kernel 2: gather + project masked rows --------------------
// lane-per-row. W read with wave-uniform indices -> scalar (s_load) promotion,
// no LDS. writes tgtm[rank][c] = -2*t_c and t2arr[rank] = ||t||^2.
__global__ __launch_bounds__(256) void project_kernel(const float* __restrict__ x,
                                                      const int* __restrict__ mask,
                                                      const int* __restrict__ chunkpref,
                                                      const float* __restrict__ W,
                                                      float* __restrict__ tgtm,
                                                      float* __restrict__ t2arr) {
  int tid  = threadIdx.x;
  int wave = blockIdx.x * 4 + (tid >> 6);        // 128 blocks * 4 waves = 512
  int lane = tid & 63;
  int row  = wave * 64 + lane;
  int m = mask[row];
  unsigned long long bal = __ballot(m != 0);
  int rank = chunkpref[wave] + __popcll(bal & ((1ull << lane) - 1ull));
  if (!m) return;

  const float4* xr = (const float4*)(x + (long)row * D);
  float pd[CDIM];
#pragma unroll
  for (int c = 0; c < CDIM; ++c) pd[c] = 0.f;
#pragma unroll 2
  for (int j = 0; j < D / 4; ++j) {              // 80 float4 per row
    float4 xv = xr[j];
#pragma unroll
    for (int c = 0; c < CDIM; ++c) {             // uniform -> s_load_dwordx4
      const float4 wv = *(const float4*)(W + c * D + j * 4);
      float acc = fmaf(xv.x, wv.x, pd[c]);
      acc = fmaf(xv.y, wv.y, acc);
      acc = fmaf(xv.z, wv.z, acc);
      pd[c] = fmaf(xv.w, wv.w, acc);
    }
  }
  float t2 = 0.f;
#pragma unroll
  for (int c = 0; c < CDIM; ++c) t2 = fmaf(pd[c], pd[c], t2);
  float* op = tgtm + (long)rank * CDIM;
#pragma unroll
  for (int c = 0; c < CDIM; ++c) op[c] = -2.0f * pd[c];
  t2arr[rank] = t2;
}

// ---------------- Kernel 3: distances + global argmin + finish --------------
// 1024 blocks: rowblk = bid>>6 (16 x 1024 rows), seg = bid&63 (64 x 128 codes).
// 4 rows/thread in registers (64 VGPR, no spill). Codes read wave-uniformly
// from global (s_load) with A/B double-buffer prefetch. val = c2[k] + (-2t).c;
// t2 added once per row at pack time (doesn't change per-row argmin).
#define LOADC(BUF, B2, IDX)                                          \
  {                                                                  \
    const float* cbp = cbk + ((long)(IDX) << 4);                     \
    _Pragma("unroll")                                                \
    for (int i = 0; i < 16; ++i) BUF[i] = cbp[i];                    \
    B2 = c2[IDX];                                                    \
  }

#define COMPUTE(BUF, BC2, KIDX)                                      \
  {                                                                  \
    _Pragma("unroll")                                                \
    for (int rr = 0; rr < 4; ++rr) {                                 \
      float acc = fmaf(tm[rr][0], BUF[0], BC2);                      \
      _Pragma("unroll")                                              \
      for (int i = 1; i < 16; ++i)                                   \
        acc = fmaf(tm[rr][i], BUF[i], acc);                          \
      if (acc < minv[rr]) { minv[rr] = acc; mink[rr] = (KIDX); }     \
    }                                                                \
  }

__global__ __launch_bounds__(256, 3) void argmin_kernel(const float* __restrict__ tgtm,
                                                        const float* __restrict__ t2arr,
                                                        const float* __restrict__ cbk,
                                                        const float* __restrict__ c2,
                                                        unsigned long long* __restrict__ keys,
                                                        unsigned int* __restrict__ counter,
                                                        int* __restrict__ out) {
  __shared__ unsigned long long red[256];
  int tid    = threadIdx.x;
  int bid    = (int)blockIdx.x;
  int rowblk = bid >> 6;                         // 16 row blocks of 1024 rows
  int seg    = bid & 63;                         // 64 code segments of 128
  int k0     = seg << 7;

  float tm[4][CDIM];
  float t2r[4];
#pragma unroll
  for (int rr = 0; rr < 4; ++rr) {
    int r = rowblk * 1024 + tid + rr * 256;
    const float4* tp = (const float4*)(tgtm + (long)r * CDIM);
#pragma unroll
    for (int q = 0; q < 4; ++q) {
      float4 v = tp[q];
      tm[rr][q * 4 + 0] = v.x; tm[rr][q * 4 + 1] = v.y;
      tm[rr][q * 4 + 2] = v.z; tm[rr][q * 4 + 3] = v.w;
    }
    t2r[rr] = t2arr[r];
  }

  float minv[4]; int mink[4];
#pragma unroll
  for (int rr = 0; rr < 4; ++rr) { minv[rr] = 3.4e38f; mink[rr] = 0; }

  float bufA[16], bufB[16], a2, b2;
  LOADC(bufA, a2, k0);
  for (int kk = 0; kk < 128; kk += 2) {
    LOADC(bufB, b2, k0 + ((kk + 1) & 127));      // prefetch next (wraps, in-bounds)
    COMPUTE(bufA, a2, kk);
    LOADC(bufA, a2, k0 + ((kk + 2) & 127));      // prefetch next-next
    COMPUTE(bufB, b2, kk + 1);
  }

  // pack (monotone float bits << 32) | flat_index; u64-min => first-index tie-break
  unsigned long long best = 0xFFFFFFFFFFFFFFFFull;
  int rbase = rowblk * 1024 + tid;
#pragma unroll
  for (int rr = 0; rr < 4; ++rr) {
    float tot = t2r[rr] + minv[rr];
    unsigned int u = __float_as_uint(tot);
    u = (u & 0x80000000u) ? ~u : (u | 0x80000000u);
    unsigned int flat = (unsigned int)(rbase + rr * 256) * (unsigned int)NCODES
                      + (unsigned int)(k0 + mink[rr]);
    unsigned long long kk2 = ((unsigned long long)u << 32) | (unsigned long long)flat;
    best = (kk2 < best) ? kk2 : best;
  }
  red[tid] = best;
  __syncthreads();
  for (int s = 128; s > 0; s >>= 1) {
    if (tid < s) { if (red[tid + s] < red[tid]) red[tid] = red[tid + s]; }
    __syncthreads();
  }
  if (tid == 0) {
    atomicMin(&keys[bid & 7], red[0]);           // 8-way spread -> low contention
    __threadfence();
    unsigned int prev = atomicAdd(counter, 1u);
    if (prev == (unsigned int)gridDim.x - 1u) {  // last block: reduce + emit
      unsigned long long m = 0xFFFFFFFFFFFFFFFFull;
#pragma unroll
      for (int i = 0; i < 8; ++i) {
        unsigned long long v = atomicMin(&keys[i], 0xFFFFFFFFFFFFFFFFull); // coherent read
        m = (v < m) ? v : m;
      }
      out[0] = (int)(unsigned int)(m & 0xFFFFFFFFull);
    }
  }
}

extern "C" void kernel_launch(void* const* d_in, const int* in_sizes, int n_in,
                              void* d_out, int out_size, void* d_ws, size_t ws_size,
                              hipStream_t stream) {
  const float* x    = (const float*)d_in[0];   // (16,2048,320)
  const int*   mask = (const int*)d_in[1];     // (16,2048)
  const float* W    = (const float*)d_in[2];   // (16,320)
  const float* cbk  = (const float*)d_in[3];   // (8192,16)
  int* out = (int*)d_out;

  char* ws = (char*)d_ws;
  int*                chunkpref = (int*)ws;                          // 2 KiB
  unsigned long long* keys      = (unsigned long long*)(ws + 2048);  // 64 B
  unsigned int*       counter   = (unsigned int*)(ws + 2112);        // 4 B
  float*              c2        = (float*)(ws + 4096);               // 32 KiB
  float*              t2arr     = (float*)(ws + 36864);              // 64 KiB
  float*              tgtm      = (float*)(ws + 102400);             // 1 MiB

  prep_kernel<<<17, 512, 0, stream>>>(mask, cbk, chunkpref, c2, keys, counter);
  project_kernel<<<128, 256, 0, stream>>>(x, mask, chunkpref, W, tgtm, t2arr);
  argmin_kernel<<<1024, 256, 0, stream>>>(tgtm, t2arr, cbk, c2, keys, counter, out);
}